// Round 1
// baseline (7252.911 us; speedup 1.0000x reference)
//
#include <hip/hip_runtime.h>
#include <math.h>

#define S_LEN   2048
#define HIDDEN  4096
#define N_HEADS 32
#define N_KV    8
#define HEAD_DIM 128
#define NCAND   1844      // S - RECENT
#define HEAVY_K 819
#define MASK_LEN 2049     // S + 1

// ---------------------------------------------------------------------------
// f32 GEMM: C[M,N] = A[M,K] * B[K,N].  Tile 64x64, K-tile 32, 4x4 micro-tile.
// As stored transposed [k][m] with +4 pad so float4 reads stay aligned and
// the transpose stores are only mildly (4-way) conflicted.
// ---------------------------------------------------------------------------
__global__ __launch_bounds__(256) void gemm_f32(
    const float* __restrict__ A, const float* __restrict__ B,
    float* __restrict__ C, int M, int N, int K)
{
  __shared__ float As[32][68];
  __shared__ float Bs[32][64];
  const int t  = threadIdx.x;
  const int tx = t & 15;
  const int ty = t >> 4;
  const int bm = blockIdx.y << 6;
  const int bn = blockIdx.x << 6;
  const int ar = t >> 3;   // 0..31 (A row within tile; +32 for second)
  const int ac = t & 7;    // 0..7  (A float4 col within k-tile)
  const int br = t >> 4;   // 0..15 (B k-row; +16 for second)
  const int bc = t & 15;   // 0..15 (B float4 col)
  const float4* A4 = (const float4*)A;
  const float4* B4 = (const float4*)B;
  const int K4 = K >> 2;
  const int N4 = N >> 2;

  float acc[4][4];
#pragma unroll
  for (int i = 0; i < 4; i++) {
    acc[i][0] = 0.f; acc[i][1] = 0.f; acc[i][2] = 0.f; acc[i][3] = 0.f;
  }

  for (int k0 = 0; k0 < K; k0 += 32) {
    float4 a0 = A4[(size_t)(bm + ar)      * K4 + (k0 >> 2) + ac];
    float4 a1 = A4[(size_t)(bm + ar + 32) * K4 + (k0 >> 2) + ac];
    float4 b0 = B4[(size_t)(k0 + br)      * N4 + (bn >> 2) + bc];
    float4 b1 = B4[(size_t)(k0 + br + 16) * N4 + (bn >> 2) + bc];
    __syncthreads();
    As[ac*4+0][ar]      = a0.x; As[ac*4+1][ar]      = a0.y;
    As[ac*4+2][ar]      = a0.z; As[ac*4+3][ar]      = a0.w;
    As[ac*4+0][ar + 32] = a1.x; As[ac*4+1][ar + 32] = a1.y;
    As[ac*4+2][ar + 32] = a1.z; As[ac*4+3][ar + 32] = a1.w;
    *(float4*)&Bs[br][bc*4]      = b0;
    *(float4*)&Bs[br + 16][bc*4] = b1;
    __syncthreads();
#pragma unroll
    for (int kk = 0; kk < 32; kk++) {
      const float4 av = *(const float4*)&As[kk][ty*4];
      const float4 bv = *(const float4*)&Bs[kk][tx*4];
      acc[0][0] += av.x*bv.x; acc[0][1] += av.x*bv.y; acc[0][2] += av.x*bv.z; acc[0][3] += av.x*bv.w;
      acc[1][0] += av.y*bv.x; acc[1][1] += av.y*bv.y; acc[1][2] += av.y*bv.z; acc[1][3] += av.y*bv.w;
      acc[2][0] += av.z*bv.x; acc[2][1] += av.z*bv.y; acc[2][2] += av.z*bv.z; acc[2][3] += av.z*bv.w;
      acc[3][0] += av.w*bv.x; acc[3][1] += av.w*bv.y; acc[3][2] += av.w*bv.z; acc[3][3] += av.w*bv.w;
    }
  }
#pragma unroll
  for (int i = 0; i < 4; i++) {
    float4 o;
    o.x = acc[i][0]; o.y = acc[i][1]; o.z = acc[i][2]; o.w = acc[i][3];
    *(float4*)&C[(size_t)(bm + ty*4 + i) * N + bn + tx*4] = o;
  }
}

// ---------------------------------------------------------------------------
// In-place RoPE.  inv_freq computed in f64 then rounded to f32 so it matches
// numpy's correctly-rounded f32 pow (a 1-ulp mismatch would shift angles by
// ~2e-4 rad at p~2047 and could flip top-k picks).
// ---------------------------------------------------------------------------
__global__ __launch_bounds__(256) void rope_kernel(
    float* __restrict__ buf, const int* __restrict__ pos_ids, int ncols)
{
  __shared__ float invf_s[64];
  if (threadIdx.x < 64)
    invf_s[threadIdx.x] =
        (float)(1.0 / pow(10000.0, (double)threadIdx.x * (1.0 / 64.0)));
  __syncthreads();

  int i = blockIdx.x * 256 + threadIdx.x;
  int half = ncols >> 1;
  int total = S_LEN * half;
  if (i >= total) return;
  int row = i / half;
  int rem = i - row * half;
  int hh = rem >> 6;
  int d  = rem & 63;
  float p = (float)pos_ids[row];
  float ang = p * invf_s[d];
  float c = cosf(ang);
  float s = sinf(ang);
  float* base = buf + (size_t)row * ncols + hh * HEAD_DIM;
  float x0 = base[d];
  float x1 = base[d + 64];
  base[d]      = x0 * c - x1 * s;
  base[d + 64] = x1 * c + x0 * s;
}

// ---------------------------------------------------------------------------
// Attention pass 1: per-row max (m) and softmax denominator (l).
// Block = 32 q-rows of one head; 2x2 micro-tile (rows ty/ty+16, cols tx/tx+16).
// LDS rows padded to 132 floats to kill the 128-float bank aliasing.
// ---------------------------------------------------------------------------
__global__ __launch_bounds__(256) void attn_pass1(
    const float* __restrict__ Qr, const float* __restrict__ Kr,
    float* __restrict__ Mrow, float* __restrict__ Lrow)
{
  const int qt = blockIdx.x;
  const int h  = blockIdx.y;
  const int q0 = qt << 5;
  const int kvh = h >> 2;
  __shared__ float Qs[32 * 132];
  __shared__ float Ks[32 * 132];
  const int t  = threadIdx.x;
  const int tx = t & 15;
  const int ty = t >> 4;
  const float SCALE = 1.0f / sqrtf(128.0f);

  for (int i = t; i < 32 * 32; i += 256) {
    int r = i >> 5, c4 = i & 31;
    float4 v = ((const float4*)Qr)[(size_t)(q0 + r) * (HIDDEN / 4) + h * 32 + c4];
    *(float4*)(Qs + r * 132 + c4 * 4) = v;
  }

  const int r0 = ty, r1 = ty + 16;
  float m0 = -INFINITY, l0 = 0.f, m1 = -INFINITY, l1 = 0.f;

  for (int kt = 0; kt <= qt; kt++) {
    const int k0 = kt << 5;
    __syncthreads();
    for (int i = t; i < 32 * 32; i += 256) {
      int r = i >> 5, c4 = i & 31;
      float4 v = ((const float4*)Kr)[(size_t)(k0 + r) * (N_KV * HEAD_DIM / 4) + kvh * 32 + c4];
      *(float4*)(Ks + r * 132 + c4 * 4) = v;
    }
    __syncthreads();

    float s00 = 0.f, s01 = 0.f, s10 = 0.f, s11 = 0.f;
    const float* qa = Qs + r0 * 132;
    const float* qb = Qs + r1 * 132;
    const float* ka = Ks + tx * 132;
    const float* kb = Ks + (tx + 16) * 132;
#pragma unroll
    for (int kk = 0; kk < 128; kk += 4) {
      float4 a0 = *(const float4*)(qa + kk);
      float4 a1 = *(const float4*)(qb + kk);
      float4 b0 = *(const float4*)(ka + kk);
      float4 b1 = *(const float4*)(kb + kk);
      s00 += a0.x*b0.x + a0.y*b0.y + a0.z*b0.z + a0.w*b0.w;
      s01 += a0.x*b1.x + a0.y*b1.y + a0.z*b1.z + a0.w*b1.w;
      s10 += a1.x*b0.x + a1.y*b0.y + a1.z*b0.z + a1.w*b0.w;
      s11 += a1.x*b1.x + a1.y*b1.y + a1.z*b1.z + a1.w*b1.w;
    }
    s00 *= SCALE; s01 *= SCALE; s10 *= SCALE; s11 *= SCALE;

    if (k0 + tx      <= q0 + r0) { float mn = fmaxf(m0, s00); l0 = l0*expf(m0-mn) + expf(s00-mn); m0 = mn; }
    if (k0 + tx + 16 <= q0 + r0) { float mn = fmaxf(m0, s01); l0 = l0*expf(m0-mn) + expf(s01-mn); m0 = mn; }
    if (k0 + tx      <= q0 + r1) { float mn = fmaxf(m1, s10); l1 = l1*expf(m1-mn) + expf(s10-mn); m1 = mn; }
    if (k0 + tx + 16 <= q0 + r1) { float mn = fmaxf(m1, s11); l1 = l1*expf(m1-mn) + expf(s11-mn); m1 = mn; }
  }

  // merge the 16 lanes that share each row (lanes are consecutive in-wave)
#pragma unroll
  for (int off = 1; off < 16; off <<= 1) {
    float mo = __shfl_xor(m0, off);
    float lo = __shfl_xor(l0, off);
    float mn = fmaxf(m0, mo);
    if (mn > -INFINITY) l0 = l0 * expf(m0 - mn) + lo * expf(mo - mn);
    m0 = mn;
    mo = __shfl_xor(m1, off);
    lo = __shfl_xor(l1, off);
    mn = fmaxf(m1, mo);
    if (mn > -INFINITY) l1 = l1 * expf(m1 - mn) + lo * expf(mo - mn);
    m1 = mn;
  }
  if (tx == 0) {
    Mrow[h * S_LEN + q0 + r0] = m0; Lrow[h * S_LEN + q0 + r0] = l0;
    Mrow[h * S_LEN + q0 + r1] = m1; Lrow[h * S_LEN + q0 + r1] = l1;
  }
}

// ---------------------------------------------------------------------------
// Attention pass 2: weights with final (m,l); per-tile column sums ->
// atomicAdd into current_scores; PV accumulation into registers; write
// attn_pre in [s][h*128+d] layout so the Wo GEMM is a plain row-major GEMM.
// ---------------------------------------------------------------------------
__global__ __launch_bounds__(256) void attn_pass2(
    const float* __restrict__ Qr, const float* __restrict__ Kr,
    const float* __restrict__ Vr,
    const float* __restrict__ Mrow, const float* __restrict__ Lrow,
    float* __restrict__ cs, float* __restrict__ attn)
{
  const int qt = blockIdx.x;
  const int h  = blockIdx.y;
  const int q0 = qt << 5;
  const int kvh = h >> 2;
  __shared__ float Qs[32 * 132];
  __shared__ float Ks[32 * 132];
  __shared__ float Vs[32 * 132];
  __shared__ float Ps[32 * 33];
  const int t  = threadIdx.x;
  const int tx = t & 15;
  const int ty = t >> 4;
  const float SCALE = 1.0f / sqrtf(128.0f);

  for (int i = t; i < 32 * 32; i += 256) {
    int r = i >> 5, c4 = i & 31;
    float4 v = ((const float4*)Qr)[(size_t)(q0 + r) * (HIDDEN / 4) + h * 32 + c4];
    *(float4*)(Qs + r * 132 + c4 * 4) = v;
  }

  const int r0 = ty, r1 = ty + 16;
  const float mA = Mrow[h * S_LEN + q0 + r0];
  const float iA = 1.0f / Lrow[h * S_LEN + q0 + r0];
  const float mB = Mrow[h * S_LEN + q0 + r1];
  const float iB = 1.0f / Lrow[h * S_LEN + q0 + r1];

  float4 o00 = {0,0,0,0}, o01 = {0,0,0,0}, o10 = {0,0,0,0}, o11 = {0,0,0,0};

  for (int kt = 0; kt <= qt; kt++) {
    const int k0 = kt << 5;
    __syncthreads();
    for (int i = t; i < 32 * 32; i += 256) {
      int r = i >> 5, c4 = i & 31;
      size_t g = (size_t)(k0 + r) * (N_KV * HEAD_DIM / 4) + kvh * 32 + c4;
      *(float4*)(Ks + r * 132 + c4 * 4) = ((const float4*)Kr)[g];
      *(float4*)(Vs + r * 132 + c4 * 4) = ((const float4*)Vr)[g];
    }
    __syncthreads();

    float s00 = 0.f, s01 = 0.f, s10 = 0.f, s11 = 0.f;
    const float* qa = Qs + r0 * 132;
    const float* qb = Qs + r1 * 132;
    const float* ka = Ks + tx * 132;
    const float* kb = Ks + (tx + 16) * 132;
#pragma unroll
    for (int kk = 0; kk < 128; kk += 4) {
      float4 a0 = *(const float4*)(qa + kk);
      float4 a1 = *(const float4*)(qb + kk);
      float4 b0 = *(const float4*)(ka + kk);
      float4 b1 = *(const float4*)(kb + kk);
      s00 += a0.x*b0.x + a0.y*b0.y + a0.z*b0.z + a0.w*b0.w;
      s01 += a0.x*b1.x + a0.y*b1.y + a0.z*b1.z + a0.w*b1.w;
      s10 += a1.x*b0.x + a1.y*b0.y + a1.z*b0.z + a1.w*b0.w;
      s11 += a1.x*b1.x + a1.y*b1.y + a1.z*b1.z + a1.w*b1.w;
    }

    float w00 = (k0 + tx      <= q0 + r0) ? expf(s00 * SCALE - mA) * iA : 0.f;
    float w01 = (k0 + tx + 16 <= q0 + r0) ? expf(s01 * SCALE - mA) * iA : 0.f;
    float w10 = (k0 + tx      <= q0 + r1) ? expf(s10 * SCALE - mB) * iB : 0.f;
    float w11 = (k0 + tx + 16 <= q0 + r1) ? expf(s11 * SCALE - mB) * iB : 0.f;
    Ps[r0 * 33 + tx]      = w00;
    Ps[r0 * 33 + tx + 16] = w01;
    Ps[r1 * 33 + tx]      = w10;
    Ps[r1 * 33 + tx + 16] = w11;
    __syncthreads();

    if (t < 32) {
      float sum = 0.f;
#pragma unroll
      for (int r = 0; r < 32; r++) sum += Ps[r * 33 + t];
      atomicAdd(&cs[h * S_LEN + k0 + t], sum);
    }

#pragma unroll 8
    for (int c = 0; c < 32; c++) {
      float w0 = Ps[r0 * 33 + c];
      float w1 = Ps[r1 * 33 + c];
      float4 va = *(const float4*)(Vs + c * 132 + tx * 4);
      float4 vb = *(const float4*)(Vs + c * 132 + 64 + tx * 4);
      o00.x += w0*va.x; o00.y += w0*va.y; o00.z += w0*va.z; o00.w += w0*va.w;
      o01.x += w0*vb.x; o01.y += w0*vb.y; o01.z += w0*vb.z; o01.w += w0*vb.w;
      o10.x += w1*va.x; o10.y += w1*va.y; o10.z += w1*va.z; o10.w += w1*va.w;
      o11.x += w1*vb.x; o11.y += w1*vb.y; o11.z += w1*vb.z; o11.w += w1*vb.w;
    }
  }

  float* ob0 = attn + (size_t)(q0 + r0) * HIDDEN + h * HEAD_DIM;
  float* ob1 = attn + (size_t)(q0 + r1) * HIDDEN + h * HEAD_DIM;
  *(float4*)(ob0 + tx * 4)      = o00;
  *(float4*)(ob0 + 64 + tx * 4) = o01;
  *(float4*)(ob1 + tx * 4)      = o10;
  *(float4*)(ob1 + 64 + tx * 4) = o11;
}

// ---------------------------------------------------------------------------
// Exact top-HEAVY_K of the first NCAND scores per head via O(n^2) ranking.
// rank(i) = #{j: s[j] > s[i]} + #{j<i: s[j]==s[i]}  (== lax.top_k tie-break).
// Mask layout: [0..1843]=topk hits, [1844]=0, [1845..2048]=1.
// ---------------------------------------------------------------------------
__global__ __launch_bounds__(256) void topk_mask_kernel(
    const float* __restrict__ cs, float* __restrict__ maskout)
{
  const int h = blockIdx.x;
  __shared__ float sv[NCAND];
  const float* s = cs + h * S_LEN;
  const int t = threadIdx.x;
  for (int i = t; i < NCAND; i += 256) sv[i] = s[i];
  __syncthreads();

  float v[8];
  int cnt[8];
#pragma unroll
  for (int j = 0; j < 8; j++) {
    int i = t + j * 256;
    v[j] = (i < NCAND) ? sv[i] : INFINITY;
    cnt[j] = 0;
  }
  for (int jj = 0; jj < NCAND; jj++) {
    float x = sv[jj];
#pragma unroll
    for (int j = 0; j < 8; j++) {
      int i = t + j * 256;
      cnt[j] += ((x > v[j]) || (x == v[j] && jj < i)) ? 1 : 0;
    }
  }

  float* mrow = maskout + h * MASK_LEN;
  for (int i = t; i < MASK_LEN; i += 256)
    mrow[i] = (i >= NCAND + 1) ? 1.0f : 0.0f;
#pragma unroll
  for (int j = 0; j < 8; j++) {
    int i = t + j * 256;
    if (i < NCAND && cnt[j] < HEAVY_K) mrow[i] = 1.0f;
  }
}

__global__ __launch_bounds__(256) void zero_kernel(float* __restrict__ p, int n)
{
  int i = blockIdx.x * 256 + threadIdx.x;
  if (i < n) p[i] = 0.f;
}

// ---------------------------------------------------------------------------
extern "C" void kernel_launch(void* const* d_in, const int* in_sizes, int n_in,
                              void* d_out, int out_size, void* d_ws, size_t ws_size,
                              hipStream_t stream)
{
  (void)in_sizes; (void)n_in; (void)out_size; (void)ws_size;
  const float* hs = (const float*)d_in[0];
  const int*  pos = (const int*)d_in[1];
  const float* Wq = (const float*)d_in[2];
  const float* Wk = (const float*)d_in[3];
  const float* Wv = (const float*)d_in[4];
  const float* Wo = (const float*)d_in[5];
  float* out = (float*)d_out;

  // workspace layout (floats): ~84.7 MB total
  float* Qraw = (float*)d_ws;                               // 2048*4096
  float* Kraw = Qraw + (size_t)S_LEN * HIDDEN;              // 2048*1024
  float* Vraw = Kraw + (size_t)S_LEN * N_KV * HEAD_DIM;     // 2048*1024
  float* attn = Vraw + (size_t)S_LEN * N_KV * HEAD_DIM;     // 2048*4096
  float* Mrow = attn + (size_t)S_LEN * HIDDEN;              // 32*2048
  float* Lrow = Mrow + (size_t)N_HEADS * S_LEN;             // 32*2048
  float* cs   = Lrow + (size_t)N_HEADS * S_LEN;             // 32*2048

  dim3 blk(256);

  gemm_f32<<<dim3(HIDDEN / 64, S_LEN / 64), blk, 0, stream>>>(
      hs, Wq, Qraw, S_LEN, HIDDEN, HIDDEN);
  gemm_f32<<<dim3((N_KV * HEAD_DIM) / 64, S_LEN / 64), blk, 0, stream>>>(
      hs, Wk, Kraw, S_LEN, N_KV * HEAD_DIM, HIDDEN);
  gemm_f32<<<dim3((N_KV * HEAD_DIM) / 64, S_LEN / 64), blk, 0, stream>>>(
      hs, Wv, Vraw, S_LEN, N_KV * HEAD_DIM, HIDDEN);

  rope_kernel<<<(S_LEN * (HIDDEN / 2) + 255) / 256, blk, 0, stream>>>(
      Qraw, pos, HIDDEN);
  rope_kernel<<<(S_LEN * (N_KV * HEAD_DIM / 2) + 255) / 256, blk, 0, stream>>>(
      Kraw, pos, N_KV * HEAD_DIM);

  attn_pass1<<<dim3(S_LEN / 32, N_HEADS), blk, 0, stream>>>(
      Qraw, Kraw, Mrow, Lrow);

  zero_kernel<<<(N_HEADS * S_LEN + 255) / 256, blk, 0, stream>>>(
      cs, N_HEADS * S_LEN);

  attn_pass2<<<dim3(S_LEN / 32, N_HEADS), blk, 0, stream>>>(
      Qraw, Kraw, Vraw, Mrow, Lrow, cs, attn);

  topk_mask_kernel<<<N_HEADS, blk, 0, stream>>>(
      cs, out + (size_t)S_LEN * HIDDEN);

  gemm_f32<<<dim3(HIDDEN / 64, S_LEN / 64), blk, 0, stream>>>(
      attn, Wo, out, S_LEN, HIDDEN, HIDDEN);
}

// Round 2
// 5000.314 us; speedup vs baseline: 1.4505x; 1.4505x over previous
//
#include <hip/hip_runtime.h>
#include <math.h>

#define S_LEN   2048
#define HIDDEN  4096
#define N_HEADS 32
#define N_KV    8
#define HEAD_DIM 128
#define NCAND   1844      // S - RECENT
#define HEAVY_K 819
#define MASK_LEN 2049     // S + 1

// ---------------------------------------------------------------------------
// f32 GEMM: C[M,N] = A[M,K] * B[K,N].  Tile 64x64, K-tile 32, 4x4 micro-tile.
// ---------------------------------------------------------------------------
__global__ __launch_bounds__(256) void gemm_f32(
    const float* __restrict__ A, const float* __restrict__ B,
    float* __restrict__ C, int M, int N, int K)
{
  __shared__ float As[32][68];
  __shared__ float Bs[32][64];
  const int t  = threadIdx.x;
  const int tx = t & 15;
  const int ty = t >> 4;
  const int bm = blockIdx.y << 6;
  const int bn = blockIdx.x << 6;
  const int ar = t >> 3;   // 0..31 (A row within tile; +32 for second)
  const int ac = t & 7;    // 0..7  (A float4 col within k-tile)
  const int br = t >> 4;   // 0..15 (B k-row; +16 for second)
  const int bc = t & 15;   // 0..15 (B float4 col)
  const float4* A4 = (const float4*)A;
  const float4* B4 = (const float4*)B;
  const int K4 = K >> 2;
  const int N4 = N >> 2;

  float acc[4][4];
#pragma unroll
  for (int i = 0; i < 4; i++) {
    acc[i][0] = 0.f; acc[i][1] = 0.f; acc[i][2] = 0.f; acc[i][3] = 0.f;
  }

  for (int k0 = 0; k0 < K; k0 += 32) {
    float4 a0 = A4[(size_t)(bm + ar)      * K4 + (k0 >> 2) + ac];
    float4 a1 = A4[(size_t)(bm + ar + 32) * K4 + (k0 >> 2) + ac];
    float4 b0 = B4[(size_t)(k0 + br)      * N4 + (bn >> 2) + bc];
    float4 b1 = B4[(size_t)(k0 + br + 16) * N4 + (bn >> 2) + bc];
    __syncthreads();
    As[ac*4+0][ar]      = a0.x; As[ac*4+1][ar]      = a0.y;
    As[ac*4+2][ar]      = a0.z; As[ac*4+3][ar]      = a0.w;
    As[ac*4+0][ar + 32] = a1.x; As[ac*4+1][ar + 32] = a1.y;
    As[ac*4+2][ar + 32] = a1.z; As[ac*4+3][ar + 32] = a1.w;
    *(float4*)&Bs[br][bc*4]      = b0;
    *(float4*)&Bs[br + 16][bc*4] = b1;
    __syncthreads();
#pragma unroll
    for (int kk = 0; kk < 32; kk++) {
      const float4 av = *(const float4*)&As[kk][ty*4];
      const float4 bv = *(const float4*)&Bs[kk][tx*4];
      acc[0][0] += av.x*bv.x; acc[0][1] += av.x*bv.y; acc[0][2] += av.x*bv.z; acc[0][3] += av.x*bv.w;
      acc[1][0] += av.y*bv.x; acc[1][1] += av.y*bv.y; acc[1][2] += av.y*bv.z; acc[1][3] += av.y*bv.w;
      acc[2][0] += av.z*bv.x; acc[2][1] += av.z*bv.y; acc[2][2] += av.z*bv.z; acc[2][3] += av.z*bv.w;
      acc[3][0] += av.w*bv.x; acc[3][1] += av.w*bv.y; acc[3][2] += av.w*bv.z; acc[3][3] += av.w*bv.w;
    }
  }
#pragma unroll
  for (int i = 0; i < 4; i++) {
    float4 o;
    o.x = acc[i][0]; o.y = acc[i][1]; o.z = acc[i][2]; o.w = acc[i][3];
    *(float4*)&C[(size_t)(bm + ty*4 + i) * N + bn + tx*4] = o;
  }
}

// ---------------------------------------------------------------------------
// In-place RoPE.  inv_freq via f64 pow then rounded to f32 (matches numpy).
// ---------------------------------------------------------------------------
__global__ __launch_bounds__(256) void rope_kernel(
    float* __restrict__ buf, const int* __restrict__ pos_ids, int ncols)
{
  __shared__ float invf_s[64];
  if (threadIdx.x < 64)
    invf_s[threadIdx.x] =
        (float)(1.0 / pow(10000.0, (double)threadIdx.x * (1.0 / 64.0)));
  __syncthreads();

  int i = blockIdx.x * 256 + threadIdx.x;
  int half = ncols >> 1;
  int total = S_LEN * half;
  if (i >= total) return;
  int row = i / half;
  int rem = i - row * half;
  int hh = rem >> 6;
  int d  = rem & 63;
  float p = (float)pos_ids[row];
  float ang = p * invf_s[d];
  float c = cosf(ang);
  float s = sinf(ang);
  float* base = buf + (size_t)row * ncols + hh * HEAD_DIM;
  float x0 = base[d];
  float x1 = base[d + 64];
  base[d]      = x0 * c - x1 * s;
  base[d + 64] = x1 * c + x0 * s;
}

// ---------------------------------------------------------------------------
// Attention pass 1: softmax denominator only, no max subtraction.
// Scores are bounded (|s*SCALE| <~ 15) so exp() cannot overflow f32; the
// max-free softmax differs from the max-subtracted one by ~2 ulp relative,
// far below the top-k rank gaps.  No online chain, no divergent updates.
// qt reversed so the longest (qt=63) blocks dispatch first.
// ---------------------------------------------------------------------------
__global__ __launch_bounds__(256, 4) void attn_pass1(
    const float* __restrict__ Qr, const float* __restrict__ Kr,
    float* __restrict__ Lrow)
{
  const int qt = gridDim.x - 1 - blockIdx.x;   // big blocks first
  const int h  = blockIdx.y;
  const int q0 = qt << 5;
  const int kvh = h >> 2;
  __shared__ float Qs[32 * 132];
  __shared__ float Ks[32 * 132];
  const int t  = threadIdx.x;
  const int tx = t & 15;
  const int ty = t >> 4;
  const float SCALE = 1.0f / sqrtf(128.0f);

  for (int i = t; i < 32 * 32; i += 256) {
    int r = i >> 5, c4 = i & 31;
    float4 v = ((const float4*)Qr)[(size_t)(q0 + r) * (HIDDEN / 4) + h * 32 + c4];
    *(float4*)(Qs + r * 132 + c4 * 4) = v;
  }

  const int r0 = ty, r1 = ty + 16;
  float l0 = 0.f, l1 = 0.f;

  for (int kt = 0; kt <= qt; kt++) {
    const int k0 = kt << 5;
    __syncthreads();
    for (int i = t; i < 32 * 32; i += 256) {
      int r = i >> 5, c4 = i & 31;
      float4 v = ((const float4*)Kr)[(size_t)(k0 + r) * (N_KV * HEAD_DIM / 4) + kvh * 32 + c4];
      *(float4*)(Ks + r * 132 + c4 * 4) = v;
    }
    __syncthreads();

    float s00 = 0.f, s01 = 0.f, s10 = 0.f, s11 = 0.f;
    const float* qa = Qs + r0 * 132;
    const float* qb = Qs + r1 * 132;
    const float* ka = Ks + tx * 132;
    const float* kb = Ks + (tx + 16) * 132;
#pragma unroll
    for (int kk = 0; kk < 128; kk += 4) {
      float4 a0 = *(const float4*)(qa + kk);
      float4 a1 = *(const float4*)(qb + kk);
      float4 b0 = *(const float4*)(ka + kk);
      float4 b1 = *(const float4*)(kb + kk);
      s00 += a0.x*b0.x + a0.y*b0.y + a0.z*b0.z + a0.w*b0.w;
      s01 += a0.x*b1.x + a0.y*b1.y + a0.z*b1.z + a0.w*b1.w;
      s10 += a1.x*b0.x + a1.y*b0.y + a1.z*b0.z + a1.w*b0.w;
      s11 += a1.x*b1.x + a1.y*b1.y + a1.z*b1.z + a1.w*b1.w;
    }
    l0 += (k0 + tx      <= q0 + r0) ? expf(s00 * SCALE) : 0.f;
    l0 += (k0 + tx + 16 <= q0 + r0) ? expf(s01 * SCALE) : 0.f;
    l1 += (k0 + tx      <= q0 + r1) ? expf(s10 * SCALE) : 0.f;
    l1 += (k0 + tx + 16 <= q0 + r1) ? expf(s11 * SCALE) : 0.f;
  }

  // sum across the 16 lanes sharing each row (consecutive in-wave)
#pragma unroll
  for (int off = 1; off < 16; off <<= 1) {
    l0 += __shfl_xor(l0, off);
    l1 += __shfl_xor(l1, off);
  }
  if (tx == 0) {
    Lrow[h * S_LEN + q0 + r0] = l0;
    Lrow[h * S_LEN + q0 + r1] = l1;
  }
}

// ---------------------------------------------------------------------------
// Attention pass 2: w = exp(s*SCALE)/l; per-tile column sums -> atomicAdd
// into current_scores; PV accumulation; write attn in [s][h*128+d] layout.
// Vs unpadded (its reads are row-broadcast) so 3 blocks fit per CU.
// ---------------------------------------------------------------------------
__global__ __launch_bounds__(256, 4) void attn_pass2(
    const float* __restrict__ Qr, const float* __restrict__ Kr,
    const float* __restrict__ Vr, const float* __restrict__ Lrow,
    float* __restrict__ cs, float* __restrict__ attn)
{
  const int qt = gridDim.x - 1 - blockIdx.x;   // big blocks first
  const int h  = blockIdx.y;
  const int q0 = qt << 5;
  const int kvh = h >> 2;
  __shared__ float Qs[32 * 132];
  __shared__ float Ks[32 * 132];
  __shared__ float Vs[32 * 128];
  __shared__ float Ps[32 * 33];
  const int t  = threadIdx.x;
  const int tx = t & 15;
  const int ty = t >> 4;
  const float SCALE = 1.0f / sqrtf(128.0f);

  for (int i = t; i < 32 * 32; i += 256) {
    int r = i >> 5, c4 = i & 31;
    float4 v = ((const float4*)Qr)[(size_t)(q0 + r) * (HIDDEN / 4) + h * 32 + c4];
    *(float4*)(Qs + r * 132 + c4 * 4) = v;
  }

  const int r0 = ty, r1 = ty + 16;
  const float iA = 1.0f / Lrow[h * S_LEN + q0 + r0];
  const float iB = 1.0f / Lrow[h * S_LEN + q0 + r1];

  float4 o00 = {0,0,0,0}, o01 = {0,0,0,0}, o10 = {0,0,0,0}, o11 = {0,0,0,0};

  for (int kt = 0; kt <= qt; kt++) {
    const int k0 = kt << 5;
    __syncthreads();
    for (int i = t; i < 32 * 32; i += 256) {
      int r = i >> 5, c4 = i & 31;
      size_t g = (size_t)(k0 + r) * (N_KV * HEAD_DIM / 4) + kvh * 32 + c4;
      *(float4*)(Ks + r * 132 + c4 * 4) = ((const float4*)Kr)[g];
      *(float4*)(Vs + r * 128 + c4 * 4) = ((const float4*)Vr)[g];
    }
    __syncthreads();

    float s00 = 0.f, s01 = 0.f, s10 = 0.f, s11 = 0.f;
    const float* qa = Qs + r0 * 132;
    const float* qb = Qs + r1 * 132;
    const float* ka = Ks + tx * 132;
    const float* kb = Ks + (tx + 16) * 132;
#pragma unroll
    for (int kk = 0; kk < 128; kk += 4) {
      float4 a0 = *(const float4*)(qa + kk);
      float4 a1 = *(const float4*)(qb + kk);
      float4 b0 = *(const float4*)(ka + kk);
      float4 b1 = *(const float4*)(kb + kk);
      s00 += a0.x*b0.x + a0.y*b0.y + a0.z*b0.z + a0.w*b0.w;
      s01 += a0.x*b1.x + a0.y*b1.y + a0.z*b1.z + a0.w*b1.w;
      s10 += a1.x*b0.x + a1.y*b0.y + a1.z*b0.z + a1.w*b0.w;
      s11 += a1.x*b1.x + a1.y*b1.y + a1.z*b1.z + a1.w*b1.w;
    }

    float w00 = (k0 + tx      <= q0 + r0) ? expf(s00 * SCALE) * iA : 0.f;
    float w01 = (k0 + tx + 16 <= q0 + r0) ? expf(s01 * SCALE) * iA : 0.f;
    float w10 = (k0 + tx      <= q0 + r1) ? expf(s10 * SCALE) * iB : 0.f;
    float w11 = (k0 + tx + 16 <= q0 + r1) ? expf(s11 * SCALE) * iB : 0.f;
    Ps[r0 * 33 + tx]      = w00;
    Ps[r0 * 33 + tx + 16] = w01;
    Ps[r1 * 33 + tx]      = w10;
    Ps[r1 * 33 + tx + 16] = w11;
    __syncthreads();

    if (t < 32) {
      float sum = 0.f;
#pragma unroll
      for (int r = 0; r < 32; r++) sum += Ps[r * 33 + t];
      atomicAdd(&cs[h * S_LEN + k0 + t], sum);
    }

#pragma unroll 8
    for (int c = 0; c < 32; c++) {
      float w0 = Ps[r0 * 33 + c];
      float w1 = Ps[r1 * 33 + c];
      float4 va = *(const float4*)(Vs + c * 128 + tx * 4);
      float4 vb = *(const float4*)(Vs + c * 128 + 64 + tx * 4);
      o00.x += w0*va.x; o00.y += w0*va.y; o00.z += w0*va.z; o00.w += w0*va.w;
      o01.x += w0*vb.x; o01.y += w0*vb.y; o01.z += w0*vb.z; o01.w += w0*vb.w;
      o10.x += w1*va.x; o10.y += w1*va.y; o10.z += w1*va.z; o10.w += w1*va.w;
      o11.x += w1*vb.x; o11.y += w1*vb.y; o11.z += w1*vb.z; o11.w += w1*vb.w;
    }
  }

  float* ob0 = attn + (size_t)(q0 + r0) * HIDDEN + h * HEAD_DIM;
  float* ob1 = attn + (size_t)(q0 + r1) * HIDDEN + h * HEAD_DIM;
  *(float4*)(ob0 + tx * 4)      = o00;
  *(float4*)(ob0 + 64 + tx * 4) = o01;
  *(float4*)(ob1 + tx * 4)      = o10;
  *(float4*)(ob1 + 64 + tx * 4) = o11;
}

// ---------------------------------------------------------------------------
// Exact top-HEAVY_K of the first NCAND scores per head via O(n^2) ranking.
// ---------------------------------------------------------------------------
__global__ __launch_bounds__(256) void topk_mask_kernel(
    const float* __restrict__ cs, float* __restrict__ maskout)
{
  const int h = blockIdx.x;
  __shared__ float sv[NCAND];
  const float* s = cs + h * S_LEN;
  const int t = threadIdx.x;
  for (int i = t; i < NCAND; i += 256) sv[i] = s[i];
  __syncthreads();

  float v[8];
  int cnt[8];
#pragma unroll
  for (int j = 0; j < 8; j++) {
    int i = t + j * 256;
    v[j] = (i < NCAND) ? sv[i] : INFINITY;
    cnt[j] = 0;
  }
  for (int jj = 0; jj < NCAND; jj++) {
    float x = sv[jj];
#pragma unroll
    for (int j = 0; j < 8; j++) {
      int i = t + j * 256;
      cnt[j] += ((x > v[j]) || (x == v[j] && jj < i)) ? 1 : 0;
    }
  }

  float* mrow = maskout + h * MASK_LEN;
  for (int i = t; i < MASK_LEN; i += 256)
    mrow[i] = (i >= NCAND + 1) ? 1.0f : 0.0f;
#pragma unroll
  for (int j = 0; j < 8; j++) {
    int i = t + j * 256;
    if (i < NCAND && cnt[j] < HEAVY_K) mrow[i] = 1.0f;
  }
}

__global__ __launch_bounds__(256) void zero_kernel(float* __restrict__ p, int n)
{
  int i = blockIdx.x * 256 + threadIdx.x;
  if (i < n) p[i] = 0.f;
}

// ---------------------------------------------------------------------------
extern "C" void kernel_launch(void* const* d_in, const int* in_sizes, int n_in,
                              void* d_out, int out_size, void* d_ws, size_t ws_size,
                              hipStream_t stream)
{
  (void)in_sizes; (void)n_in; (void)out_size; (void)ws_size;
  const float* hs = (const float*)d_in[0];
  const int*  pos = (const int*)d_in[1];
  const float* Wq = (const float*)d_in[2];
  const float* Wk = (const float*)d_in[3];
  const float* Wv = (const float*)d_in[4];
  const float* Wo = (const float*)d_in[5];
  float* out = (float*)d_out;

  float* Qraw = (float*)d_ws;                               // 2048*4096
  float* Kraw = Qraw + (size_t)S_LEN * HIDDEN;              // 2048*1024
  float* Vraw = Kraw + (size_t)S_LEN * N_KV * HEAD_DIM;     // 2048*1024
  float* attn = Vraw + (size_t)S_LEN * N_KV * HEAD_DIM;     // 2048*4096
  float* Lrow = attn + (size_t)S_LEN * HIDDEN;              // 32*2048
  float* cs   = Lrow + (size_t)N_HEADS * S_LEN;             // 32*2048

  dim3 blk(256);

  gemm_f32<<<dim3(HIDDEN / 64, S_LEN / 64), blk, 0, stream>>>(
      hs, Wq, Qraw, S_LEN, HIDDEN, HIDDEN);
  gemm_f32<<<dim3((N_KV * HEAD_DIM) / 64, S_LEN / 64), blk, 0, stream>>>(
      hs, Wk, Kraw, S_LEN, N_KV * HEAD_DIM, HIDDEN);
  gemm_f32<<<dim3((N_KV * HEAD_DIM) / 64, S_LEN / 64), blk, 0, stream>>>(
      hs, Wv, Vraw, S_LEN, N_KV * HEAD_DIM, HIDDEN);

  rope_kernel<<<(S_LEN * (HIDDEN / 2) + 255) / 256, blk, 0, stream>>>(
      Qraw, pos, HIDDEN);
  rope_kernel<<<(S_LEN * (N_KV * HEAD_DIM / 2) + 255) / 256, blk, 0, stream>>>(
      Kraw, pos, N_KV * HEAD_DIM);

  attn_pass1<<<dim3(S_LEN / 32, N_HEADS), blk, 0, stream>>>(
      Qraw, Kraw, Lrow);

  zero_kernel<<<(N_HEADS * S_LEN + 255) / 256, blk, 0, stream>>>(
      cs, N_HEADS * S_LEN);

  attn_pass2<<<dim3(S_LEN / 32, N_HEADS), blk, 0, stream>>>(
      Qraw, Kraw, Vraw, Lrow, cs, attn);

  topk_mask_kernel<<<N_HEADS, blk, 0, stream>>>(
      cs, out + (size_t)S_LEN * HIDDEN);

  gemm_f32<<<dim3(HIDDEN / 64, S_LEN / 64), blk, 0, stream>>>(
      attn, Wo, out, S_LEN, HIDDEN, HIDDEN);
}

// Round 3
// 3988.097 us; speedup vs baseline: 1.8186x; 1.2538x over previous
//
#include <hip/hip_runtime.h>
#include <math.h>

#define S_LEN   2048
#define HIDDEN  4096
#define N_HEADS 32
#define N_KV    8
#define HEAD_DIM 128
#define NCAND   1844      // S - RECENT
#define HEAVY_K 819
#define MASK_LEN 2049     // S + 1

using bf16x8 = __attribute__((ext_vector_type(8))) short;
using f32x4  = __attribute__((ext_vector_type(4))) float;

__device__ inline unsigned short f2bf(float x) {
  unsigned u = __builtin_bit_cast(unsigned, x);
  unsigned r = (u + 0x7FFFu + ((u >> 16) & 1u)) >> 16;
  return (unsigned short)r;
}

// ---------------------------------------------------------------------------
// f32 GEMM: C[M,N] = A[M,K] * B[K,N].  Tile 64x64, K-tile 32, 4x4 micro-tile.
// Used ONLY for the mask-critical Wq / Wk projections (bit-identical to R2).
// ---------------------------------------------------------------------------
__global__ __launch_bounds__(256) void gemm_f32(
    const float* __restrict__ A, const float* __restrict__ B,
    float* __restrict__ C, int M, int N, int K)
{
  __shared__ float As[32][68];
  __shared__ float Bs[32][64];
  const int t  = threadIdx.x;
  const int tx = t & 15;
  const int ty = t >> 4;
  const int bm = blockIdx.y << 6;
  const int bn = blockIdx.x << 6;
  const int ar = t >> 3;
  const int ac = t & 7;
  const int br = t >> 4;
  const int bc = t & 15;
  const float4* A4 = (const float4*)A;
  const float4* B4 = (const float4*)B;
  const int K4 = K >> 2;
  const int N4 = N >> 2;

  float acc[4][4];
#pragma unroll
  for (int i = 0; i < 4; i++) {
    acc[i][0] = 0.f; acc[i][1] = 0.f; acc[i][2] = 0.f; acc[i][3] = 0.f;
  }

  for (int k0 = 0; k0 < K; k0 += 32) {
    float4 a0 = A4[(size_t)(bm + ar)      * K4 + (k0 >> 2) + ac];
    float4 a1 = A4[(size_t)(bm + ar + 32) * K4 + (k0 >> 2) + ac];
    float4 b0 = B4[(size_t)(k0 + br)      * N4 + (bn >> 2) + bc];
    float4 b1 = B4[(size_t)(k0 + br + 16) * N4 + (bn >> 2) + bc];
    __syncthreads();
    As[ac*4+0][ar]      = a0.x; As[ac*4+1][ar]      = a0.y;
    As[ac*4+2][ar]      = a0.z; As[ac*4+3][ar]      = a0.w;
    As[ac*4+0][ar + 32] = a1.x; As[ac*4+1][ar + 32] = a1.y;
    As[ac*4+2][ar + 32] = a1.z; As[ac*4+3][ar + 32] = a1.w;
    *(float4*)&Bs[br][bc*4]      = b0;
    *(float4*)&Bs[br + 16][bc*4] = b1;
    __syncthreads();
#pragma unroll
    for (int kk = 0; kk < 32; kk++) {
      const float4 av = *(const float4*)&As[kk][ty*4];
      const float4 bv = *(const float4*)&Bs[kk][tx*4];
      acc[0][0] += av.x*bv.x; acc[0][1] += av.x*bv.y; acc[0][2] += av.x*bv.z; acc[0][3] += av.x*bv.w;
      acc[1][0] += av.y*bv.x; acc[1][1] += av.y*bv.y; acc[1][2] += av.y*bv.z; acc[1][3] += av.y*bv.w;
      acc[2][0] += av.z*bv.x; acc[2][1] += av.z*bv.y; acc[2][2] += av.z*bv.z; acc[2][3] += av.z*bv.w;
      acc[3][0] += av.w*bv.x; acc[3][1] += av.w*bv.y; acc[3][2] += av.w*bv.z; acc[3][3] += av.w*bv.w;
    }
  }
#pragma unroll
  for (int i = 0; i < 4; i++) {
    float4 o;
    o.x = acc[i][0]; o.y = acc[i][1]; o.z = acc[i][2]; o.w = acc[i][3];
    *(float4*)&C[(size_t)(bm + ty*4 + i) * N + bn + tx*4] = o;
  }
}

// ---------------------------------------------------------------------------
// bf16 MFMA GEMM: C(f32)[M,N] = A(bf16)[M,K] * BT(bf16)[N,K]^T.
// Tile 64x64, BK=32, 4 waves each computing a 32x32 quadrant via 2x2
// mfma_f32_16x16x32_bf16.  Row stride 40 bf16 (+8 pad): frag reads are
// conflict-free per 8-lane phase.
// A-frag: lane l holds A[m=l&15][k=(l>>4)*8+j]; B-frag: B[k][n=l&15];
// D: row=(l>>4)*4+r, col=l&15  (verified layouts, learn_hip m89/m91).
// ---------------------------------------------------------------------------
__global__ __launch_bounds__(256) void gemm_bf16(
    const unsigned short* __restrict__ A, const unsigned short* __restrict__ BT,
    float* __restrict__ C, int M, int N, int K)
{
  __shared__ unsigned short As[64 * 40];
  __shared__ unsigned short Bs[64 * 40];
  const int t    = threadIdx.x;
  const int lane = t & 63;
  const int wave = t >> 6;
  const int mbase = (wave >> 1) * 32;
  const int nbase = (wave & 1) * 32;
  const int bm = blockIdx.y << 6;
  const int bn = blockIdx.x << 6;
  const int srow = t >> 2;
  const int scol = (t & 3) * 8;
  const int l16 = lane & 15;
  const int lk  = (lane >> 4) * 8;

  f32x4 acc00 = {0.f,0.f,0.f,0.f}, acc01 = {0.f,0.f,0.f,0.f};
  f32x4 acc10 = {0.f,0.f,0.f,0.f}, acc11 = {0.f,0.f,0.f,0.f};

  for (int k0 = 0; k0 < K; k0 += 32) {
    float4 av = *(const float4*)(A  + (size_t)(bm + srow) * K + k0 + scol);
    float4 bv = *(const float4*)(BT + (size_t)(bn + srow) * K + k0 + scol);
    __syncthreads();
    *(float4*)(As + srow * 40 + scol) = av;
    *(float4*)(Bs + srow * 40 + scol) = bv;
    __syncthreads();
    bf16x8 a0 = *(const bf16x8*)(As + (mbase + l16)      * 40 + lk);
    bf16x8 a1 = *(const bf16x8*)(As + (mbase + 16 + l16) * 40 + lk);
    bf16x8 b0 = *(const bf16x8*)(Bs + (nbase + l16)      * 40 + lk);
    bf16x8 b1 = *(const bf16x8*)(Bs + (nbase + 16 + l16) * 40 + lk);
    acc00 = __builtin_amdgcn_mfma_f32_16x16x32_bf16(a0, b0, acc00, 0, 0, 0);
    acc01 = __builtin_amdgcn_mfma_f32_16x16x32_bf16(a0, b1, acc01, 0, 0, 0);
    acc10 = __builtin_amdgcn_mfma_f32_16x16x32_bf16(a1, b0, acc10, 0, 0, 0);
    acc11 = __builtin_amdgcn_mfma_f32_16x16x32_bf16(a1, b1, acc11, 0, 0, 0);
  }

  const int rr = (lane >> 4) * 4;
#pragma unroll
  for (int r = 0; r < 4; r++) {
    C[(size_t)(bm + mbase +      rr + r) * N + bn + nbase +      l16] = acc00[r];
    C[(size_t)(bm + mbase +      rr + r) * N + bn + nbase + 16 + l16] = acc01[r];
    C[(size_t)(bm + mbase + 16 + rr + r) * N + bn + nbase +      l16] = acc10[r];
    C[(size_t)(bm + mbase + 16 + rr + r) * N + bn + nbase + 16 + l16] = acc11[r];
  }
}

// ---------------------------------------------------------------------------
// f32 -> bf16 row-major convert (vectorized, grid-stride-free exact launch).
// ---------------------------------------------------------------------------
__global__ __launch_bounds__(256) void conv_rm(
    const float* __restrict__ src, unsigned short* __restrict__ dst, int n4)
{
  int i = blockIdx.x * 256 + threadIdx.x;
  if (i >= n4) return;
  float4 v = ((const float4*)src)[i];
  ushort4 o;
  o.x = f2bf(v.x); o.y = f2bf(v.y); o.z = f2bf(v.z); o.w = f2bf(v.w);
  ((ushort4*)dst)[i] = o;
}

// ---------------------------------------------------------------------------
// f32 [K][N] -> bf16 [N][K] transpose-convert, 32x32 tiles through LDS.
// ---------------------------------------------------------------------------
__global__ __launch_bounds__(256) void conv_T(
    const float* __restrict__ src, unsigned short* __restrict__ dst,
    int K, int N)
{
  __shared__ float tile[32][33];
  const int tj = blockIdx.x;   // N tile
  const int ti = blockIdx.y;   // K tile
  const int t = threadIdx.x;
  for (int idx = t; idx < 1024; idx += 256) {
    int r = idx >> 5, c = idx & 31;
    tile[r][c] = src[(size_t)(ti * 32 + r) * N + tj * 32 + c];
  }
  __syncthreads();
  for (int idx = t; idx < 1024; idx += 256) {
    int r = idx >> 5, c = idx & 31;
    dst[(size_t)(tj * 32 + r) * K + ti * 32 + c] = f2bf(tile[c][r]);
  }
}

// ---------------------------------------------------------------------------
// In-place RoPE.  inv_freq via f64 pow then rounded to f32 (matches numpy).
// ---------------------------------------------------------------------------
__global__ __launch_bounds__(256) void rope_kernel(
    float* __restrict__ buf, const int* __restrict__ pos_ids, int ncols)
{
  __shared__ float invf_s[64];
  if (threadIdx.x < 64)
    invf_s[threadIdx.x] =
        (float)(1.0 / pow(10000.0, (double)threadIdx.x * (1.0 / 64.0)));
  __syncthreads();

  int i = blockIdx.x * 256 + threadIdx.x;
  int half = ncols >> 1;
  int total = S_LEN * half;
  if (i >= total) return;
  int row = i / half;
  int rem = i - row * half;
  int hh = rem >> 6;
  int d  = rem & 63;
  float p = (float)pos_ids[row];
  float ang = p * invf_s[d];
  float c = cosf(ang);
  float s = sinf(ang);
  float* base = buf + (size_t)row * ncols + hh * HEAD_DIM;
  float x0 = base[d];
  float x1 = base[d + 64];
  base[d]      = x0 * c - x1 * s;
  base[d + 64] = x1 * c + x0 * s;
}

// ---------------------------------------------------------------------------
// Attention pass 1: softmax denominator only (max-free; |s*SCALE| <~ 15 so
// exp can't overflow and the rank-relevant ratios match to ~2 ulp).
// ---------------------------------------------------------------------------
__global__ __launch_bounds__(256, 4) void attn_pass1(
    const float* __restrict__ Qr, const float* __restrict__ Kr,
    float* __restrict__ Lrow)
{
  const int qt = gridDim.x - 1 - blockIdx.x;   // big blocks first
  const int h  = blockIdx.y;
  const int q0 = qt << 5;
  const int kvh = h >> 2;
  __shared__ float Qs[32 * 132];
  __shared__ float Ks[32 * 132];
  const int t  = threadIdx.x;
  const int tx = t & 15;
  const int ty = t >> 4;
  const float SCALE = 1.0f / sqrtf(128.0f);

  for (int i = t; i < 32 * 32; i += 256) {
    int r = i >> 5, c4 = i & 31;
    float4 v = ((const float4*)Qr)[(size_t)(q0 + r) * (HIDDEN / 4) + h * 32 + c4];
    *(float4*)(Qs + r * 132 + c4 * 4) = v;
  }

  const int r0 = ty, r1 = ty + 16;
  float l0 = 0.f, l1 = 0.f;

  for (int kt = 0; kt <= qt; kt++) {
    const int k0 = kt << 5;
    __syncthreads();
    for (int i = t; i < 32 * 32; i += 256) {
      int r = i >> 5, c4 = i & 31;
      float4 v = ((const float4*)Kr)[(size_t)(k0 + r) * (N_KV * HEAD_DIM / 4) + kvh * 32 + c4];
      *(float4*)(Ks + r * 132 + c4 * 4) = v;
    }
    __syncthreads();

    float s00 = 0.f, s01 = 0.f, s10 = 0.f, s11 = 0.f;
    const float* qa = Qs + r0 * 132;
    const float* qb = Qs + r1 * 132;
    const float* ka = Ks + tx * 132;
    const float* kb = Ks + (tx + 16) * 132;
#pragma unroll
    for (int kk = 0; kk < 128; kk += 4) {
      float4 a0 = *(const float4*)(qa + kk);
      float4 a1 = *(const float4*)(qb + kk);
      float4 b0 = *(const float4*)(ka + kk);
      float4 b1 = *(const float4*)(kb + kk);
      s00 += a0.x*b0.x + a0.y*b0.y + a0.z*b0.z + a0.w*b0.w;
      s01 += a0.x*b1.x + a0.y*b1.y + a0.z*b1.z + a0.w*b1.w;
      s10 += a1.x*b0.x + a1.y*b0.y + a1.z*b0.z + a1.w*b0.w;
      s11 += a1.x*b1.x + a1.y*b1.y + a1.z*b1.z + a1.w*b1.w;
    }
    l0 += (k0 + tx      <= q0 + r0) ? expf(s00 * SCALE) : 0.f;
    l0 += (k0 + tx + 16 <= q0 + r0) ? expf(s01 * SCALE) : 0.f;
    l1 += (k0 + tx      <= q0 + r1) ? expf(s10 * SCALE) : 0.f;
    l1 += (k0 + tx + 16 <= q0 + r1) ? expf(s11 * SCALE) : 0.f;
  }

#pragma unroll
  for (int off = 1; off < 16; off <<= 1) {
    l0 += __shfl_xor(l0, off);
    l1 += __shfl_xor(l1, off);
  }
  if (tx == 0) {
    Lrow[h * S_LEN + q0 + r0] = l0;
    Lrow[h * S_LEN + q0 + r1] = l1;
  }
}

// ---------------------------------------------------------------------------
// Attention pass 2: w = exp(s*SCALE)/l; column sums -> atomicAdd into cs;
// PV accumulation; attn written as bf16 [s][h*128+d] (output path tolerance
// is ~2%; bf16 costs ~0.3%).  LDS 53888 B -> 3 blocks/CU (was 54784 = 2).
// ---------------------------------------------------------------------------
__global__ __launch_bounds__(256, 4) void attn_pass2(
    const float* __restrict__ Qr, const float* __restrict__ Kr,
    const float* __restrict__ Vr, const float* __restrict__ Lrow,
    float* __restrict__ cs, unsigned short* __restrict__ attnb)
{
  const int qt = gridDim.x - 1 - blockIdx.x;   // big blocks first
  const int h  = blockIdx.y;
  const int q0 = qt << 5;
  const int kvh = h >> 2;
  __shared__ float Qs[32 * 128];
  __shared__ float Ks[32 * 132];
  __shared__ float Vs[32 * 128];
  __shared__ float Ps[32 * 33];
  const int t  = threadIdx.x;
  const int tx = t & 15;
  const int ty = t >> 4;
  const float SCALE = 1.0f / sqrtf(128.0f);

  for (int i = t; i < 32 * 32; i += 256) {
    int r = i >> 5, c4 = i & 31;
    float4 v = ((const float4*)Qr)[(size_t)(q0 + r) * (HIDDEN / 4) + h * 32 + c4];
    *(float4*)(Qs + r * 128 + c4 * 4) = v;
  }

  const int r0 = ty, r1 = ty + 16;
  const float iA = 1.0f / Lrow[h * S_LEN + q0 + r0];
  const float iB = 1.0f / Lrow[h * S_LEN + q0 + r1];

  float4 o00 = {0,0,0,0}, o01 = {0,0,0,0}, o10 = {0,0,0,0}, o11 = {0,0,0,0};

  for (int kt = 0; kt <= qt; kt++) {
    const int k0 = kt << 5;
    __syncthreads();
    for (int i = t; i < 32 * 32; i += 256) {
      int r = i >> 5, c4 = i & 31;
      size_t g = (size_t)(k0 + r) * (N_KV * HEAD_DIM / 4) + kvh * 32 + c4;
      *(float4*)(Ks + r * 132 + c4 * 4) = ((const float4*)Kr)[g];
      *(float4*)(Vs + r * 128 + c4 * 4) = ((const float4*)Vr)[g];
    }
    __syncthreads();

    float s00 = 0.f, s01 = 0.f, s10 = 0.f, s11 = 0.f;
    const float* qa = Qs + r0 * 128;
    const float* qb = Qs + r1 * 128;
    const float* ka = Ks + tx * 132;
    const float* kb = Ks + (tx + 16) * 132;
#pragma unroll
    for (int kk = 0; kk < 128; kk += 4) {
      float4 a0 = *(const float4*)(qa + kk);
      float4 a1 = *(const float4*)(qb + kk);
      float4 b0 = *(const float4*)(ka + kk);
      float4 b1 = *(const float4*)(kb + kk);
      s00 += a0.x*b0.x + a0.y*b0.y + a0.z*b0.z + a0.w*b0.w;
      s01 += a0.x*b1.x + a0.y*b1.y + a0.z*b1.z + a0.w*b1.w;
      s10 += a1.x*b0.x + a1.y*b0.y + a1.z*b0.z + a1.w*b0.w;
      s11 += a1.x*b1.x + a1.y*b1.y + a1.z*b1.z + a1.w*b1.w;
    }

    float w00 = (k0 + tx      <= q0 + r0) ? expf(s00 * SCALE) * iA : 0.f;
    float w01 = (k0 + tx + 16 <= q0 + r0) ? expf(s01 * SCALE) * iA : 0.f;
    float w10 = (k0 + tx      <= q0 + r1) ? expf(s10 * SCALE) * iB : 0.f;
    float w11 = (k0 + tx + 16 <= q0 + r1) ? expf(s11 * SCALE) * iB : 0.f;
    Ps[r0 * 33 + tx]      = w00;
    Ps[r0 * 33 + tx + 16] = w01;
    Ps[r1 * 33 + tx]      = w10;
    Ps[r1 * 33 + tx + 16] = w11;
    __syncthreads();

    if (t < 32) {
      float sum = 0.f;
#pragma unroll
      for (int r = 0; r < 32; r++) sum += Ps[r * 33 + t];
      atomicAdd(&cs[h * S_LEN + k0 + t], sum);
    }

#pragma unroll 8
    for (int c = 0; c < 32; c++) {
      float w0 = Ps[r0 * 33 + c];
      float w1 = Ps[r1 * 33 + c];
      float4 va = *(const float4*)(Vs + c * 128 + tx * 4);
      float4 vb = *(const float4*)(Vs + c * 128 + 64 + tx * 4);
      o00.x += w0*va.x; o00.y += w0*va.y; o00.z += w0*va.z; o00.w += w0*va.w;
      o01.x += w0*vb.x; o01.y += w0*vb.y; o01.z += w0*vb.z; o01.w += w0*vb.w;
      o10.x += w1*va.x; o10.y += w1*va.y; o10.z += w1*va.z; o10.w += w1*va.w;
      o11.x += w1*vb.x; o11.y += w1*vb.y; o11.z += w1*vb.z; o11.w += w1*vb.w;
    }
  }

  unsigned short* ob0 = attnb + (size_t)(q0 + r0) * HIDDEN + h * HEAD_DIM;
  unsigned short* ob1 = attnb + (size_t)(q0 + r1) * HIDDEN + h * HEAD_DIM;
  ushort4 p;
  p.x = f2bf(o00.x); p.y = f2bf(o00.y); p.z = f2bf(o00.z); p.w = f2bf(o00.w);
  *(ushort4*)(ob0 + tx * 4) = p;
  p.x = f2bf(o01.x); p.y = f2bf(o01.y); p.z = f2bf(o01.z); p.w = f2bf(o01.w);
  *(ushort4*)(ob0 + 64 + tx * 4) = p;
  p.x = f2bf(o10.x); p.y = f2bf(o10.y); p.z = f2bf(o10.z); p.w = f2bf(o10.w);
  *(ushort4*)(ob1 + tx * 4) = p;
  p.x = f2bf(o11.x); p.y = f2bf(o11.y); p.z = f2bf(o11.z); p.w = f2bf(o11.w);
  *(ushort4*)(ob1 + 64 + tx * 4) = p;
}

// ---------------------------------------------------------------------------
// Exact top-HEAVY_K of the first NCAND scores per head via O(n^2) ranking.
// ---------------------------------------------------------------------------
__global__ __launch_bounds__(256) void topk_mask_kernel(
    const float* __restrict__ cs, float* __restrict__ maskout)
{
  const int h = blockIdx.x;
  __shared__ float sv[NCAND];
  const float* s = cs + h * S_LEN;
  const int t = threadIdx.x;
  for (int i = t; i < NCAND; i += 256) sv[i] = s[i];
  __syncthreads();

  float v[8];
  int cnt[8];
#pragma unroll
  for (int j = 0; j < 8; j++) {
    int i = t + j * 256;
    v[j] = (i < NCAND) ? sv[i] : INFINITY;
    cnt[j] = 0;
  }
  for (int jj = 0; jj < NCAND; jj++) {
    float x = sv[jj];
#pragma unroll
    for (int j = 0; j < 8; j++) {
      int i = t + j * 256;
      cnt[j] += ((x > v[j]) || (x == v[j] && jj < i)) ? 1 : 0;
    }
  }

  float* mrow = maskout + h * MASK_LEN;
  for (int i = t; i < MASK_LEN; i += 256)
    mrow[i] = (i >= NCAND + 1) ? 1.0f : 0.0f;
#pragma unroll
  for (int j = 0; j < 8; j++) {
    int i = t + j * 256;
    if (i < NCAND && cnt[j] < HEAVY_K) mrow[i] = 1.0f;
  }
}

__global__ __launch_bounds__(256) void zero_kernel(float* __restrict__ p, int n)
{
  int i = blockIdx.x * 256 + threadIdx.x;
  if (i < n) p[i] = 0.f;
}

// ---------------------------------------------------------------------------
extern "C" void kernel_launch(void* const* d_in, const int* in_sizes, int n_in,
                              void* d_out, int out_size, void* d_ws, size_t ws_size,
                              hipStream_t stream)
{
  (void)in_sizes; (void)n_in; (void)out_size; (void)ws_size;
  const float* hs = (const float*)d_in[0];
  const int*  pos = (const int*)d_in[1];
  const float* Wq = (const float*)d_in[2];
  const float* Wk = (const float*)d_in[3];
  const float* Wv = (const float*)d_in[4];
  const float* Wo = (const float*)d_in[5];
  float* out = (float*)d_out;

  // workspace layout (~104.5 MB)
  char* w = (char*)d_ws;
  float* Qraw          = (float*)(w);                       // 32 MB
  float* Kraw          = (float*)(w + 33554432);            //  8 MB
  float* Vraw          = (float*)(w + 41943040);            //  8 MB
  float* Lrow          = (float*)(w + 50331648);            //  0.25 MB
  float* cs            = (float*)(w + 50593792);            //  0.25 MB
  unsigned short* WoT  = (unsigned short*)(w + 50855936);   // 32 MB
  unsigned short* WvT  = (unsigned short*)(w + 84410368);   //  8 MB
  unsigned short* hsb  = (unsigned short*)(w + 92798976);   // 16 MB
  unsigned short* attnb = hsb;  // overlay: hsb dead after Wv gemm

  dim3 blk(256);

  conv_rm<<<(S_LEN * HIDDEN / 4 + 255) / 256, blk, 0, stream>>>(
      hs, hsb, S_LEN * HIDDEN / 4);
  conv_T<<<dim3((N_KV * HEAD_DIM) / 32, HIDDEN / 32), blk, 0, stream>>>(
      Wv, WvT, HIDDEN, N_KV * HEAD_DIM);
  conv_T<<<dim3(HIDDEN / 32, HIDDEN / 32), blk, 0, stream>>>(
      Wo, WoT, HIDDEN, HIDDEN);

  gemm_f32<<<dim3(HIDDEN / 64, S_LEN / 64), blk, 0, stream>>>(
      hs, Wq, Qraw, S_LEN, HIDDEN, HIDDEN);
  gemm_f32<<<dim3((N_KV * HEAD_DIM) / 64, S_LEN / 64), blk, 0, stream>>>(
      hs, Wk, Kraw, S_LEN, N_KV * HEAD_DIM, HIDDEN);
  gemm_bf16<<<dim3((N_KV * HEAD_DIM) / 64, S_LEN / 64), blk, 0, stream>>>(
      hsb, WvT, Vraw, S_LEN, N_KV * HEAD_DIM, HIDDEN);

  rope_kernel<<<(S_LEN * (HIDDEN / 2) + 255) / 256, blk, 0, stream>>>(
      Qraw, pos, HIDDEN);
  rope_kernel<<<(S_LEN * (N_KV * HEAD_DIM / 2) + 255) / 256, blk, 0, stream>>>(
      Kraw, pos, N_KV * HEAD_DIM);

  attn_pass1<<<dim3(S_LEN / 32, N_HEADS), blk, 0, stream>>>(
      Qraw, Kraw, Lrow);

  zero_kernel<<<(N_HEADS * S_LEN + 255) / 256, blk, 0, stream>>>(
      cs, N_HEADS * S_LEN);

  attn_pass2<<<dim3(S_LEN / 32, N_HEADS), blk, 0, stream>>>(
      Qraw, Kraw, Vraw, Lrow, cs, attnb);

  topk_mask_kernel<<<N_HEADS, blk, 0, stream>>>(
      cs, out + (size_t)S_LEN * HIDDEN);

  gemm_bf16<<<dim3(HIDDEN / 64, S_LEN / 64), blk, 0, stream>>>(
      attnb, WoT, out, S_LEN, HIDDEN, HIDDEN);
}